// Round 1
// baseline (4901.106 us; speedup 1.0000x reference)
//
#include <hip/hip_runtime.h>
#include <math.h>

// Problem constants (from reference)
#define NB   1024
#define NK   512
#define ND   256
#define NH   8
#define HD   32
#define TK   32          // keys per staged tile
#define NT   256         // threads per block (4 waves)
#define EPSF 1e-5f
#define SCALE 0.17677669529663689f   // hd^-0.5 = 1/sqrt(32)

// Fused single-query attention, fp32 throughout (correctness anchor).
// One block per batch row. Thread tid: outg = tid&127 -> output dims {2*outg, 2*outg+1},
// keyg = tid>>7 -> key half of the 32-key tile. Head = outg>>4 (16 contiguous lanes
// per head => width-16 shuffle reductions for per-head LayerNorm + scores).
__global__ __launch_bounds__(NT, 3)
void attn_fused(const float* __restrict__ x_q,
                const float* __restrict__ x_k,
                const float* __restrict__ x_v,
                const float* __restrict__ Wq,
                const float* __restrict__ Wk,
                const float* __restrict__ Wv,
                const float* __restrict__ Wp,
                const float* __restrict__ qn_w,
                const float* __restrict__ qn_b,
                const float* __restrict__ kn_w,
                const float* __restrict__ kn_b,
                const float* __restrict__ n_w,
                const float* __restrict__ n_b,
                float* __restrict__ out)
{
    __shared__ float4 s_x4[TK * ND / 4];   // 32 KiB: staged x_k / x_v tile
    __shared__ float  s_sc[NH][NK];        // 16 KiB: scores, then softmax probs
    __shared__ float  s_q[ND];             //  1 KiB: normalized*scaled q
    __shared__ float  s_o[2][ND];          //  2 KiB: per-keyg partial attention out
    __shared__ float4 s_y4[ND / 4];        //  1 KiB: x_q staging, later LN'ed out
    __shared__ float  s_r1[NT / 64], s_r2[NT / 64];

    const int tid  = threadIdx.x;
    const int b    = blockIdx.x;
    const int outg = tid & 127;
    const int keyg = tid >> 7;
    const int h    = outg >> 4;            // head 0..7
    const int dh0  = (outg & 15) * 2;      // dim-in-head of first owned dim
    const int d0   = outg * 2;             // global out dim of first owned dim

    // ---- stage x_q[b] ----
    if (tid < ND / 4) s_y4[tid] = ((const float4*)(x_q + (size_t)b * ND))[tid];
    __syncthreads();

    // ---- q projection: thread tid computes out dim tid ----
    float qv = 0.f;
    {
        const float4* wr = (const float4*)(Wq + (size_t)tid * ND);
        for (int d4 = 0; d4 < ND / 4; ++d4) {
            float4 w = wr[d4];
            float4 x = s_y4[d4];
            qv += w.x * x.x + w.y * x.y + w.z * x.z + w.w * x.w;
        }
    }
    // ---- q LayerNorm per head (32 contiguous lanes per head) ----
    {
        float s1 = qv, s2 = qv * qv;
        #pragma unroll
        for (int m = 1; m < 32; m <<= 1) {
            s1 += __shfl_xor(s1, m, 32);
            s2 += __shfl_xor(s2, m, 32);
        }
        float mu  = s1 * (1.f / HD);
        float var = s2 * (1.f / HD) - mu * mu;
        float rs  = rsqrtf(var + EPSF);
        int   dh  = tid & (HD - 1);
        s_q[tid] = ((qv - mu) * rs * qn_w[dh] + qn_b[dh]) * SCALE;
    }
    __syncthreads();

    const float q0 = s_q[d0];
    const float q1 = s_q[d0 + 1];
    const float knw0 = kn_w[dh0], knw1 = kn_w[dh0 + 1];
    const float knb0 = kn_b[dh0], knb1 = kn_b[dh0 + 1];

    // ================= Pass A: K projection + per-head LN + scores =================
    {
        const float4* wk0 = (const float4*)(Wk + (size_t)d0 * ND);
        const float4* wk1 = (const float4*)(Wk + (size_t)(d0 + 1) * ND);
        for (int kt = 0; kt < NK / TK; ++kt) {
            const float4* gx = (const float4*)(x_k + ((size_t)b * NK + (size_t)kt * TK) * ND);
            for (int i = tid; i < TK * ND / 4; i += NT) s_x4[i] = gx[i];
            __syncthreads();

            float2 acc[16];
            #pragma unroll
            for (int j = 0; j < 16; ++j) acc[j] = make_float2(0.f, 0.f);

            for (int d4 = 0; d4 < ND / 4; ++d4) {
                float4 w0 = wk0[d4];
                float4 w1 = wk1[d4];
                #pragma unroll
                for (int j = 0; j < 16; ++j) {
                    float4 x = s_x4[(keyg * 16 + j) * (ND / 4) + d4];  // wave-broadcast read
                    acc[j].x += w0.x * x.x + w0.y * x.y + w0.z * x.z + w0.w * x.w;
                    acc[j].y += w1.x * x.x + w1.y * x.y + w1.z * x.z + w1.w * x.w;
                }
            }
            // per-key LayerNorm over the 32-dim head (16 lanes x 2 dims) + score
            #pragma unroll
            for (int j = 0; j < 16; ++j) {
                float a0 = acc[j].x, a1 = acc[j].y;
                float s1 = a0 + a1, s2 = a0 * a0 + a1 * a1;
                #pragma unroll
                for (int m = 1; m < 16; m <<= 1) {
                    s1 += __shfl_xor(s1, m, 16);
                    s2 += __shfl_xor(s2, m, 16);
                }
                float mu  = s1 * (1.f / HD);
                float var = s2 * (1.f / HD) - mu * mu;
                float rs  = rsqrtf(var + EPSF);
                float k0  = (a0 - mu) * rs * knw0 + knb0;
                float k1  = (a1 - mu) * rs * knw1 + knb1;
                float p   = q0 * k0 + q1 * k1;
                #pragma unroll
                for (int m = 1; m < 16; m <<= 1) p += __shfl_xor(p, m, 16);
                if ((outg & 15) == 0) s_sc[h][kt * TK + keyg * 16 + j] = p;
            }
            __syncthreads();
        }
    }

    // ================= softmax over K per head (32 threads per head) =================
    {
        const int hh  = tid >> 5;
        const int l32 = tid & 31;
        float mx = -1e30f;
        float ev[NK / 32];
        #pragma unroll
        for (int i = 0; i < NK / 32; ++i) mx = fmaxf(mx, s_sc[hh][l32 + 32 * i]);
        #pragma unroll
        for (int m = 1; m < 32; m <<= 1) mx = fmaxf(mx, __shfl_xor(mx, m, 32));
        float sum = 0.f;
        #pragma unroll
        for (int i = 0; i < NK / 32; ++i) {
            float e = __expf(s_sc[hh][l32 + 32 * i] - mx);
            ev[i] = e;
            sum += e;
        }
        #pragma unroll
        for (int m = 1; m < 32; m <<= 1) sum += __shfl_xor(sum, m, 32);
        float inv = 1.f / sum;
        #pragma unroll
        for (int i = 0; i < NK / 32; ++i) s_sc[hh][l32 + 32 * i] = ev[i] * inv;
    }
    __syncthreads();

    // ================= Pass B: V projection + attention-weighted accumulate =================
    float o0 = 0.f, o1 = 0.f;
    {
        const float4* wv0 = (const float4*)(Wv + (size_t)d0 * ND);
        const float4* wv1 = (const float4*)(Wv + (size_t)(d0 + 1) * ND);
        for (int kt = 0; kt < NK / TK; ++kt) {
            const float4* gx = (const float4*)(x_v + ((size_t)b * NK + (size_t)kt * TK) * ND);
            for (int i = tid; i < TK * ND / 4; i += NT) s_x4[i] = gx[i];
            __syncthreads();

            float2 acc[16];
            #pragma unroll
            for (int j = 0; j < 16; ++j) acc[j] = make_float2(0.f, 0.f);

            for (int d4 = 0; d4 < ND / 4; ++d4) {
                float4 w0 = wv0[d4];
                float4 w1 = wv1[d4];
                #pragma unroll
                for (int j = 0; j < 16; ++j) {
                    float4 x = s_x4[(keyg * 16 + j) * (ND / 4) + d4];
                    acc[j].x += w0.x * x.x + w0.y * x.y + w0.z * x.z + w0.w * x.w;
                    acc[j].y += w1.x * x.x + w1.y * x.y + w1.z * x.z + w1.w * x.w;
                }
            }
            #pragma unroll
            for (int j = 0; j < 16; ++j) {
                float p = s_sc[h][kt * TK + keyg * 16 + j];
                o0 += p * acc[j].x;
                o1 += p * acc[j].y;
            }
            __syncthreads();
        }
    }
    s_o[keyg][d0]     = o0;
    s_o[keyg][d0 + 1] = o1;
    __syncthreads();

    // ================= final LayerNorm over 256 dims + output projection =================
    {
        float ov = s_o[0][tid] + s_o[1][tid];
        float s1 = ov, s2 = ov * ov;
        #pragma unroll
        for (int m = 1; m < 64; m <<= 1) {
            s1 += __shfl_xor(s1, m, 64);
            s2 += __shfl_xor(s2, m, 64);
        }
        const int w = tid >> 6;
        if ((tid & 63) == 0) { s_r1[w] = s1; s_r2[w] = s2; }
        __syncthreads();
        s1 = s_r1[0] + s_r1[1] + s_r1[2] + s_r1[3];
        s2 = s_r2[0] + s_r2[1] + s_r2[2] + s_r2[3];
        float mu  = s1 * (1.f / ND);
        float var = s2 * (1.f / ND) - mu * mu;
        float rs  = rsqrtf(var + EPSF);
        ((float*)s_y4)[tid] = (ov - mu) * rs * n_w[tid] + n_b[tid];
    }
    __syncthreads();
    {
        const float4* wr = (const float4*)(Wp + (size_t)tid * ND);
        float acc = 0.f;
        for (int d4 = 0; d4 < ND / 4; ++d4) {
            float4 w = wr[d4];
            float4 x = s_y4[d4];
            acc += w.x * x.x + w.y * x.y + w.z * x.z + w.w * x.w;
        }
        out[(size_t)b * ND + tid] = acc;
    }
}

extern "C" void kernel_launch(void* const* d_in, const int* in_sizes, int n_in,
                              void* d_out, int out_size, void* d_ws, size_t ws_size,
                              hipStream_t stream)
{
    attn_fused<<<NB, NT, 0, stream>>>(
        (const float*)d_in[0],   // x_q
        (const float*)d_in[1],   // x_k
        (const float*)d_in[2],   // x_v
        (const float*)d_in[3],   // Wq
        (const float*)d_in[4],   // Wk
        (const float*)d_in[5],   // Wv
        (const float*)d_in[6],   // Wp
        (const float*)d_in[7],   // qn_w
        (const float*)d_in[8],   // qn_b
        (const float*)d_in[9],   // kn_w
        (const float*)d_in[10],  // kn_b
        (const float*)d_in[11],  // n_w
        (const float*)d_in[12],  // n_b
        (float*)d_out);
}